// Round 1
// baseline (72.671 us; speedup 1.0000x reference)
//
#include <hip/hip_runtime.h>

#define C_DIM 512
#define HID   256
#define B_DIM 8
#define L_DIM 196
#define LT    14      // l-tile per block in GEMM phase (196 = 14*14)

// Phase 1: p1[b,l,h] = sum_c f1[b,c,l] * W1[c,h] + b1[h]
//          p2[b,l,h] = sum_c f2[b,c,l] * W1[C+c,h]
// grid = (B * L/LT, 2), block = 256 (thread = h)
__global__ __launch_bounds__(256) void compute_p_kernel(
    const float* __restrict__ f1, const float* __restrict__ f2,
    const float* __restrict__ W1, const float* __restrict__ b1,
    float* __restrict__ p1, float* __restrict__ p2) {
  const int which = blockIdx.y;                 // 0 -> p1, 1 -> p2
  const int bt = blockIdx.x;                    // 0 .. B*(L/LT)-1
  const int b  = bt / (L_DIM / LT);
  const int l0 = (bt % (L_DIM / LT)) * LT;
  const float* __restrict__ f = which ? f2 : f1;
  const float* __restrict__ W = W1 + which * C_DIM * HID;
  float* __restrict__ p = which ? p2 : p1;

  __shared__ float fv[C_DIM][LT];               // 28 KB
  for (int idx = threadIdx.x; idx < C_DIM * LT; idx += 256) {
    const int c  = idx / LT;
    const int lt = idx - c * LT;
    fv[c][lt] = f[(b * C_DIM + c) * L_DIM + l0 + lt];
  }

  const int h = threadIdx.x;
  const float bias = which ? 0.0f : b1[h];      // fold b1 into p1
  float acc[LT];
  #pragma unroll
  for (int lt = 0; lt < LT; ++lt) acc[lt] = bias;
  __syncthreads();

  #pragma unroll 4
  for (int c = 0; c < C_DIM; ++c) {
    const float w = W[c * HID + h];             // coalesced over h
    #pragma unroll
    for (int lt = 0; lt < LT; ++lt)
      acc[lt] = fmaf(fv[c][lt], w, acc[lt]);    // fv read is LDS broadcast
  }

  #pragma unroll
  for (int lt = 0; lt < LT; ++lt)
    p[(b * L_DIM + l0 + lt) * HID + h] = acc[lt];
}

// Phase 2: partial[b,i] = sum_j relu(p1[b,i,:] + p2[b,j,:]) . W2
// one wave handles i0 and i0+98; lane owns 4 h-channels.
// grid = B*98/4 = 196 blocks, block = 256 (4 waves)
__global__ __launch_bounds__(256) void pair_kernel(
    const float* __restrict__ p1, const float* __restrict__ p2,
    const float* __restrict__ W2, float* __restrict__ partial) {
  const int lane = threadIdx.x & 63;
  const int wid  = blockIdx.x * 4 + (threadIdx.x >> 6);  // 0..783
  const int b    = wid / (L_DIM / 2);
  const int i0   = wid % (L_DIM / 2);

  const float4 w  = *(const float4*)(W2 + lane * 4);
  const float4 a1 = *(const float4*)(p1 + (b * L_DIM + i0) * HID + lane * 4);
  const float4 a2 = *(const float4*)(p1 + (b * L_DIM + i0 + 98) * HID + lane * 4);

  const float* __restrict__ p2b = p2 + b * L_DIM * HID;
  float acc1 = 0.0f, acc2 = 0.0f;
  for (int j = 0; j < L_DIM; ++j) {
    const float4 v = *(const float4*)(p2b + j * HID + lane * 4);
    float t;
    t = fmaxf(a1.x + v.x, 0.0f); acc1 = fmaf(t, w.x, acc1);
    t = fmaxf(a1.y + v.y, 0.0f); acc1 = fmaf(t, w.y, acc1);
    t = fmaxf(a1.z + v.z, 0.0f); acc1 = fmaf(t, w.z, acc1);
    t = fmaxf(a1.w + v.w, 0.0f); acc1 = fmaf(t, w.w, acc1);
    t = fmaxf(a2.x + v.x, 0.0f); acc2 = fmaf(t, w.x, acc2);
    t = fmaxf(a2.y + v.y, 0.0f); acc2 = fmaf(t, w.y, acc2);
    t = fmaxf(a2.z + v.z, 0.0f); acc2 = fmaf(t, w.z, acc2);
    t = fmaxf(a2.w + v.w, 0.0f); acc2 = fmaf(t, w.w, acc2);
  }

  // wave-64 reduction
  #pragma unroll
  for (int off = 32; off > 0; off >>= 1) {
    acc1 += __shfl_down(acc1, off);
    acc2 += __shfl_down(acc2, off);
  }
  if (lane == 0) {
    partial[b * L_DIM + i0]      = acc1;
    partial[b * L_DIM + i0 + 98] = acc2;
  }
}

// Phase 3: out[b] = sum_i partial[b,i] + L*L*b2[0]
// grid = B, block = 64
__global__ __launch_bounds__(64) void reduce_kernel(
    const float* __restrict__ partial, const float* __restrict__ b2,
    float* __restrict__ out) {
  const int b = blockIdx.x;
  const int lane = threadIdx.x;
  float acc = 0.0f;
  for (int j = lane; j < L_DIM; j += 64) acc += partial[b * L_DIM + j];
  #pragma unroll
  for (int off = 32; off > 0; off >>= 1) acc += __shfl_down(acc, off);
  if (lane == 0)
    out[b] = acc + (float)(L_DIM * L_DIM) * b2[0];
}

extern "C" void kernel_launch(void* const* d_in, const int* in_sizes, int n_in,
                              void* d_out, int out_size, void* d_ws, size_t ws_size,
                              hipStream_t stream) {
  const float* f1 = (const float*)d_in[0];   // [B, C, 14, 14]
  const float* f2 = (const float*)d_in[1];
  const float* W1 = (const float*)d_in[2];   // [2C, HID]
  const float* b1 = (const float*)d_in[3];   // [HID]
  const float* W2 = (const float*)d_in[4];   // [HID, 1]
  const float* b2 = (const float*)d_in[5];   // [1]
  float* out = (float*)d_out;                // [B, 1]

  float* p1      = (float*)d_ws;                       // B*L*HID
  float* p2      = p1 + B_DIM * L_DIM * HID;           // B*L*HID
  float* partial = p2 + B_DIM * L_DIM * HID;           // B*L

  dim3 g1(B_DIM * (L_DIM / LT), 2);
  compute_p_kernel<<<g1, 256, 0, stream>>>(f1, f2, W1, b1, p1, p2);

  pair_kernel<<<(B_DIM * (L_DIM / 2)) / 4, 256, 0, stream>>>(p1, p2, W2, partial);

  reduce_kernel<<<B_DIM, 64, 0, stream>>>(partial, b2, out);
}

// Round 2
// 50.112 us; speedup vs baseline: 1.4502x; 1.4502x over previous
//
#include <hip/hip_runtime.h>

#define C_DIM 512
#define HID   256
#define B_DIM 8
#define L_DIM 196
#define LT    14            // l-tile per block (196 = 14*14)
#define NCH   4             // c-split chunks per block
#define CCH   (C_DIM/NCH)   // 128 c per chunk
#define NJC   4             // j-chunks in pair phase
#define JCL   (L_DIM/NJC)   // 49 j per chunk

// Phase 1: p1[b,l,h] = sum_c f1[b,c,l]*W1[c,h] + b1[h]
//          p2[b,l,h] = sum_c f2[b,c,l]*W1[C+c,h]
// grid = (B*14, 2), block = 1024: h = tid&255, chunk = tid>>8 owns 128 c's.
__global__ __launch_bounds__(1024) void compute_p_kernel(
    const float* __restrict__ f1, const float* __restrict__ f2,
    const float* __restrict__ W1, const float* __restrict__ b1,
    float* __restrict__ p1, float* __restrict__ p2) {
  const int which = blockIdx.y;
  const int bt = blockIdx.x;
  const int b  = bt / (L_DIM / LT);
  const int l0 = (bt % (L_DIM / LT)) * LT;
  const int h     = threadIdx.x & (HID - 1);
  const int chunk = threadIdx.x >> 8;            // 0..3

  const float* __restrict__ f = which ? f2 : f1;
  const float* __restrict__ W = W1 + which * C_DIM * HID;
  float* __restrict__ p = which ? p2 : p1;

  __shared__ float fv[C_DIM][LT];                // 28672 B
  __shared__ float comb[2][HID][LT + 1];         // 30720 B (pad 15 -> no bank conflict)

  for (int idx = threadIdx.x; idx < C_DIM * LT; idx += 1024) {
    const int c  = idx / LT;
    const int lt = idx - c * LT;
    fv[c][lt] = f[(b * C_DIM + c) * L_DIM + l0 + lt];
  }

  float acc[LT];
  #pragma unroll
  for (int lt = 0; lt < LT; ++lt) acc[lt] = 0.0f;
  __syncthreads();

  const float* __restrict__ Wc = W + (chunk * CCH) * HID + h;
  const int c0 = chunk * CCH;
  #pragma unroll 8
  for (int c = 0; c < CCH; ++c) {
    const float w = Wc[c * HID];                 // coalesced over h
    #pragma unroll
    for (int lt = 0; lt < LT; ++lt)
      acc[lt] = fmaf(fv[c0 + c][lt], w, acc[lt]); // LDS broadcast
  }

  // tree-combine the 4 chunks: {2,3} -> comb, {0,1} add; 1 -> comb, 0 adds+stores
  if (chunk >= 2) {
    #pragma unroll
    for (int lt = 0; lt < LT; ++lt) comb[chunk - 2][h][lt] = acc[lt];
  }
  __syncthreads();
  if (chunk < 2) {
    #pragma unroll
    for (int lt = 0; lt < LT; ++lt) acc[lt] += comb[chunk][h][lt];
  }
  __syncthreads();
  if (chunk == 1) {
    #pragma unroll
    for (int lt = 0; lt < LT; ++lt) comb[0][h][lt] = acc[lt];
  }
  __syncthreads();
  if (chunk == 0) {
    const float bias = which ? 0.0f : b1[h];     // fold b1 into p1 only
    #pragma unroll
    for (int lt = 0; lt < LT; ++lt)
      p[(b * L_DIM + l0 + lt) * HID + h] = acc[lt] + comb[0][h][lt] + bias;
  }
}

// Phase 2: partial[b,jc,i] = sum_{j in chunk jc} relu(p1[b,i,:]+p2[b,j,:]).W2
// wave covers 4 i-rows (wi, wi+49, wi+98, wi+147) and one 49-j chunk.
// 1568 waves -> 392 blocks; the 4 waves of a block share the same p2 stream.
__global__ __launch_bounds__(256) void pair_kernel(
    const float* __restrict__ p1, const float* __restrict__ p2,
    const float* __restrict__ W2, float* __restrict__ partial) {
  const int lane = threadIdx.x & 63;
  const int wid  = blockIdx.x * 4 + (threadIdx.x >> 6);  // 0..1567
  const int b  = wid / (NJC * JCL);                      // /196
  const int r  = wid % (NJC * JCL);
  const int jc = r / JCL;                                // 0..3 (same within block)
  const int wi = r % JCL;                                // 0..48

  const float4 w  = *(const float4*)(W2 + lane * 4);
  const float* __restrict__ p1b = p1 + (b * L_DIM) * HID + lane * 4;
  const float4 a0 = *(const float4*)(p1b + (wi          ) * HID);
  const float4 a1 = *(const float4*)(p1b + (wi + 1 * JCL) * HID);
  const float4 a2 = *(const float4*)(p1b + (wi + 2 * JCL) * HID);
  const float4 a3 = *(const float4*)(p1b + (wi + 3 * JCL) * HID);

  const float* __restrict__ p2b = p2 + (b * L_DIM + jc * JCL) * HID + lane * 4;
  float s0 = 0.f, s1 = 0.f, s2 = 0.f, s3 = 0.f;
  for (int j = 0; j < JCL; ++j) {
    const float4 v = *(const float4*)(p2b + j * HID);
    s0 = fmaf(fmaxf(a0.x + v.x, 0.f), w.x, s0);
    s1 = fmaf(fmaxf(a1.x + v.x, 0.f), w.x, s1);
    s2 = fmaf(fmaxf(a2.x + v.x, 0.f), w.x, s2);
    s3 = fmaf(fmaxf(a3.x + v.x, 0.f), w.x, s3);
    s0 = fmaf(fmaxf(a0.y + v.y, 0.f), w.y, s0);
    s1 = fmaf(fmaxf(a1.y + v.y, 0.f), w.y, s1);
    s2 = fmaf(fmaxf(a2.y + v.y, 0.f), w.y, s2);
    s3 = fmaf(fmaxf(a3.y + v.y, 0.f), w.y, s3);
    s0 = fmaf(fmaxf(a0.z + v.z, 0.f), w.z, s0);
    s1 = fmaf(fmaxf(a1.z + v.z, 0.f), w.z, s1);
    s2 = fmaf(fmaxf(a2.z + v.z, 0.f), w.z, s2);
    s3 = fmaf(fmaxf(a3.z + v.z, 0.f), w.z, s3);
    s0 = fmaf(fmaxf(a0.w + v.w, 0.f), w.w, s0);
    s1 = fmaf(fmaxf(a1.w + v.w, 0.f), w.w, s1);
    s2 = fmaf(fmaxf(a2.w + v.w, 0.f), w.w, s2);
    s3 = fmaf(fmaxf(a3.w + v.w, 0.f), w.w, s3);
  }

  #pragma unroll
  for (int off = 32; off > 0; off >>= 1) {
    s0 += __shfl_down(s0, off);
    s1 += __shfl_down(s1, off);
    s2 += __shfl_down(s2, off);
    s3 += __shfl_down(s3, off);
  }
  if (lane == 0) {
    float* pp = partial + (b * NJC + jc) * L_DIM;
    pp[wi          ] = s0;
    pp[wi + 1 * JCL] = s1;
    pp[wi + 2 * JCL] = s2;
    pp[wi + 3 * JCL] = s3;
  }
}

// Phase 3: out[b] = sum over NJC*L partials + L*L*b2
__global__ __launch_bounds__(256) void reduce_kernel(
    const float* __restrict__ partial, const float* __restrict__ b2,
    float* __restrict__ out) {
  const int b = blockIdx.x;
  const int t = threadIdx.x;
  float acc = 0.0f;
  for (int idx = t; idx < NJC * L_DIM; idx += 256)
    acc += partial[b * NJC * L_DIM + idx];
  #pragma unroll
  for (int off = 32; off > 0; off >>= 1) acc += __shfl_down(acc, off);
  __shared__ float sred[4];
  if ((t & 63) == 0) sred[t >> 6] = acc;
  __syncthreads();
  if (t == 0)
    out[b] = sred[0] + sred[1] + sred[2] + sred[3]
           + (float)(L_DIM * L_DIM) * b2[0];
}

extern "C" void kernel_launch(void* const* d_in, const int* in_sizes, int n_in,
                              void* d_out, int out_size, void* d_ws, size_t ws_size,
                              hipStream_t stream) {
  const float* f1 = (const float*)d_in[0];   // [B, C, 14, 14]
  const float* f2 = (const float*)d_in[1];
  const float* W1 = (const float*)d_in[2];   // [2C, HID]
  const float* b1 = (const float*)d_in[3];   // [HID]
  const float* W2 = (const float*)d_in[4];   // [HID, 1]
  const float* b2 = (const float*)d_in[5];   // [1]
  float* out = (float*)d_out;                // [B, 1]

  float* p1      = (float*)d_ws;                       // B*L*HID
  float* p2      = p1 + B_DIM * L_DIM * HID;           // B*L*HID
  float* partial = p2 + B_DIM * L_DIM * HID;           // B*NJC*L

  dim3 g1(B_DIM * (L_DIM / LT), 2);
  compute_p_kernel<<<g1, 1024, 0, stream>>>(f1, f2, W1, b1, p1, p2);

  pair_kernel<<<(B_DIM * NJC * JCL) / 4, 256, 0, stream>>>(p1, p2, W2, partial);

  reduce_kernel<<<B_DIM, 256, 0, stream>>>(partial, b2, out);
}